// Round 1
// baseline (545.458 us; speedup 1.0000x reference)
//
#include <hip/hip_runtime.h>
#include <cstdint>
#include <cstddef>

typedef __attribute__((ext_vector_type(8))) short short8;
typedef __attribute__((ext_vector_type(4))) float f32x4;

#define EPSF 1e-5f

__device__ __forceinline__ unsigned short f2bf(float f) {
  union { float f; unsigned u; } v; v.f = f;
  unsigned r = v.u + 0x7FFFu + ((v.u >> 16) & 1u);
  return (unsigned short)(r >> 16);
}

// ---------------------------------------------------------------- kernel A
// per (b,c): sf = mean_t, tf = mean_v, and g1vt[b][c][v][t] = bf16(g1[b][c][t][v])
__global__ __launch_bounds__(256) void k_means_tr(
    const float* __restrict__ g1, float* __restrict__ sf, float* __restrict__ tf,
    unsigned short* __restrict__ g1vt) {
  __shared__ __align__(16) float tile[1600];
  int bc = blockIdx.x;
  const float4* src = (const float4*)(g1 + (size_t)bc * 1600);
  float4* dst = (float4*)tile;
  for (int i = threadIdx.x; i < 400; i += 256) dst[i] = src[i];
  __syncthreads();
  int t = threadIdx.x;
  if (t < 64) {
    float s = 0.f;
    #pragma unroll
    for (int v = 0; v < 25; ++v) s += tile[t * 25 + v];
    tf[(size_t)bc * 64 + t] = s * (1.f / 25.f);
  } else if (t < 89) {
    int v = t - 64;
    float s = 0.f;
    for (int tt = 0; tt < 64; ++tt) s += tile[tt * 25 + v];
    sf[(size_t)bc * 25 + v] = s * (1.f / 64.f);
  }
  for (int p = threadIdx.x; p < 800; p += 256) {
    int j = p * 2;
    int v = j >> 6, tt = j & 63;
    unsigned short lo = f2bf(tile[tt * 25 + v]);
    unsigned short hi = f2bf(tile[(tt + 1) * 25 + v]);
    unsigned pack = (unsigned)lo | ((unsigned)hi << 16);
    *((unsigned*)(g1vt + (size_t)bc * 1600 + j)) = pack;
  }
}

// ---------------------------------------------------------------- kernel B (spatial attn)
__global__ __launch_bounds__(256) void k_spat(
    const float* __restrict__ sf, const float* __restrict__ sc1_w, const float* __restrict__ sc1_b,
    const float* __restrict__ sc2_w, const float* __restrict__ sc2_b,
    const float* __restrict__ As_r, const float* __restrict__ act_s,
    float* __restrict__ As_ws, float* __restrict__ out_As_at, float* __restrict__ out_As_act) {
  __shared__ float sfl[3200], w1[2048], w2[2048], s1[400], s2[400];
  int b = blockIdx.x;
  for (int i = threadIdx.x; i < 3200; i += 256) sfl[i] = sf[(size_t)b * 3200 + i];
  for (int i = threadIdx.x; i < 2048; i += 256) { w1[i] = sc1_w[i]; w2[i] = sc2_w[i]; }
  __syncthreads();
  for (int i = threadIdx.x; i < 800; i += 256) {
    if (i < 400) {
      int v = i >> 4, r = i & 15;
      float s = sc1_b[r];
      for (int c = 0; c < 128; ++c) s += w1[r * 128 + c] * sfl[c * 25 + v];
      s1[v * 16 + r] = s;
    } else {
      int j = i - 400;
      int r = j / 25, u = j % 25;
      float s = sc2_b[r];
      for (int c = 0; c < 128; ++c) s += w2[r * 128 + c] * sfl[c * 25 + u];
      s2[r * 25 + u] = s;
    }
  }
  __syncthreads();
  for (int i = threadIdx.x; i < 625; i += 256) {
    int v = i / 25, u = i % 25;
    float d = 0.f;
    #pragma unroll
    for (int r = 0; r < 16; ++r) d += s1[v * 16 + r] * s2[r * 25 + u];
    float at = d > 0.f ? tanhf(d) : 0.f;
    float act = As_r[(size_t)b * 625 + i] * act_s[i];
    out_As_at[(size_t)b * 625 + i] = at;
    out_As_act[(size_t)b * 625 + i] = act;
    As_ws[(size_t)b * 625 + i] = at + act;
  }
}

// ---------------------------------------------------------------- kernel C (temporal attn)
__global__ __launch_bounds__(256) void k_temp(
    const float* __restrict__ tf, const float* __restrict__ tc1_w, const float* __restrict__ tc1_b,
    const float* __restrict__ tc2_w, const float* __restrict__ tc2_b,
    const float* __restrict__ At_r, const float* __restrict__ act_t,
    float* __restrict__ Atev_ws, float* __restrict__ out_At_at, float* __restrict__ out_At_act) {
  __shared__ float tfl[8192], w1[2048], w2[2048], t1[1024], t2[1024];
  int b = blockIdx.x;
  for (int i = threadIdx.x; i < 8192; i += 256) tfl[i] = tf[(size_t)b * 8192 + i];
  for (int i = threadIdx.x; i < 2048; i += 256) { w1[i] = tc1_w[i]; w2[i] = tc2_w[i]; }
  __syncthreads();
  for (int i = threadIdx.x; i < 2048; i += 256) {
    if (i < 1024) {
      int t = i >> 4, r = i & 15;
      float s = tc1_b[r];
      for (int c = 0; c < 128; ++c) s += w1[r * 128 + c] * tfl[c * 64 + t];
      t1[t * 16 + r] = s;
    } else {
      int j = i - 1024;
      int r = j >> 6, t = j & 63;
      float s = tc2_b[r];
      for (int c = 0; c < 128; ++c) s += w2[r * 128 + c] * tfl[c * 64 + t];
      t2[r * 64 + t] = s;
    }
  }
  __syncthreads();
  for (int i = threadIdx.x; i < 4096; i += 256) {
    int t = i >> 6, y = i & 63;
    float d = 0.f;
    #pragma unroll
    for (int r = 0; r < 16; ++r) d += t1[t * 16 + r] * t2[r * 64 + y];
    float at = d > 0.f ? tanhf(d) : 0.f;
    float act = At_r[(size_t)b * 4096 + i] * act_t[i];
    out_At_at[(size_t)b * 4096 + i] = at;
    out_At_act[(size_t)b * 4096 + i] = act;
    if ((y & 1) == 0)
      Atev_ws[(size_t)b * 2048 + (y >> 1) * 64 + t] = at + act;  // At_ev[b][y/2][t] = At[b][t][y]
  }
}

// ---------------------------------------------------------------- kernel P (fold sp+bn into W1/W2)
__global__ __launch_bounds__(256) void k_prep(
    const float* __restrict__ W1_w, const float* __restrict__ W1_b,
    const float* __restrict__ W2_w, const float* __restrict__ W2_b,
    const float* __restrict__ sp_w, const float* __restrict__ sp_b,
    const float* __restrict__ sp_gamma, const float* __restrict__ sp_beta,
    const float* __restrict__ sp_mean, const float* __restrict__ sp_var,
    const float* __restrict__ bn_gamma, const float* __restrict__ bn_beta,
    const float* __restrict__ bn_mean, const float* __restrict__ bn_var,
    unsigned short* __restrict__ Wc1, unsigned short* __restrict__ Wc2,
    float* __restrict__ b1p, float* __restrict__ b2p,
    float* __restrict__ bnsc, float* __restrict__ bnsh) {
  __shared__ float w1row[256], w2row[256], scale[128], shift[128];
  int o = blockIdx.x;
  int t = threadIdx.x;
  w1row[t] = W1_w[o * 256 + t];
  w2row[t] = W2_w[o * 256 + t];
  if (t < 128) {
    float sc = sp_gamma[t] * rsqrtf(sp_var[t] + EPSF);
    scale[t] = sc;
    shift[t] = (sp_b[t] - sp_mean[t]) * sc + sp_beta[t];
  }
  __syncthreads();
  if (t < 128) {
    float a1 = 0.f, a2 = 0.f;
    for (int c = 0; c < 128; ++c) {
      float sw = sp_w[c * 128 + t];
      a1 += w1row[c] * scale[c] * sw;
      a2 += w2row[c] * scale[c] * sw;
    }
    Wc1[o * 256 + t] = f2bf(a1);
    Wc2[o * 256 + t] = f2bf(a2);
  } else {
    Wc1[o * 256 + t] = f2bf(w1row[t]);
    Wc2[o * 256 + t] = f2bf(w2row[t]);
  }
  if (t == 0) {
    float s = 0.f;
    for (int c = 0; c < 128; ++c) s += w1row[c] * shift[c];
    b1p[o] = W1_b[o] + s;
    float bs = bn_gamma[o] * rsqrtf(bn_var[o] + EPSF);
    bnsc[o] = bs;
    bnsh[o] = bn_beta[o] - bn_mean[o] * bs;
  } else if (t == 1) {
    float s = 0.f;
    for (int c = 0; c < 128; ++c) s += w2row[c] * shift[c];
    b2p[o] = W2_b[o] + s;
  }
}

// ---------------------------------------------------------------- kernel N (nu2 via 2-stage MFMA)
// per block: b, 8 channels. stage1: P2[y][(c,v)] = At_ev @ g1vt; stage2: nu2[c][y][u] = P2 @ As^T
__global__ __launch_bounds__(256) void k_nu2(
    const unsigned short* __restrict__ g1vt, const float* __restrict__ Atev,
    const float* __restrict__ As_ws, unsigned short* __restrict__ nu2) {
  __shared__ __align__(16) unsigned short At_l[32 * 72];   // [y][t] pad 72
  __shared__ __align__(16) unsigned short As_l[32 * 40];   // [u][v] pad 40, zero-padded
  __shared__ __align__(16) unsigned short P2_l[8 * 32 * 40]; // [c][y][v] pad 40
  int blk = blockIdx.x;
  int b = blk >> 4;
  int c0 = (blk & 15) * 8;
  int tid = threadIdx.x;
  int w = tid >> 6, l = tid & 63;
  for (int i = tid; i < 2048; i += 256)
    At_l[(i >> 6) * 72 + (i & 63)] = f2bf(Atev[(size_t)b * 2048 + i]);
  for (int i = tid; i < 1280; i += 256) As_l[i] = 0;
  for (int i = tid; i < 10240; i += 256) P2_l[i] = 0;
  __syncthreads();
  for (int i = tid; i < 625; i += 256)
    As_l[(i / 25) * 40 + (i % 25)] = f2bf(As_ws[(size_t)b * 625 + i]);
  __syncthreads();

  // stage 1: A-frags (At) preloaded
  short8 afr[2][2];
  #pragma unroll
  for (int mi = 0; mi < 2; ++mi)
    #pragma unroll
    for (int ks = 0; ks < 2; ++ks) {
      int y = mi * 16 + (l & 15);
      int tt = ks * 32 + (l >> 4) * 8;
      afr[mi][ks] = *(const short8*)(At_l + y * 72 + tt);
    }
  for (int nt = w; nt < 13; nt += 4) {
    int n = nt * 16 + (l & 15);
    int nc = n < 200 ? n : 199;
    int cc = nc / 25, vv = nc % 25;
    const unsigned short* gp = g1vt + ((size_t)(b * 128 + c0 + cc) * 25 + vv) * 64;
    short8 bfr[2];
    #pragma unroll
    for (int ks = 0; ks < 2; ++ks)
      bfr[ks] = *(const short8*)(gp + ks * 32 + (l >> 4) * 8);
    #pragma unroll
    for (int mi = 0; mi < 2; ++mi) {
      f32x4 acc = {0.f, 0.f, 0.f, 0.f};
      acc = __builtin_amdgcn_mfma_f32_16x16x32_bf16(afr[mi][0], bfr[0], acc, 0, 0, 0);
      acc = __builtin_amdgcn_mfma_f32_16x16x32_bf16(afr[mi][1], bfr[1], acc, 0, 0, 0);
      if (n < 200) {
        #pragma unroll
        for (int r = 0; r < 4; ++r) {
          int y = mi * 16 + (l >> 4) * 4 + r;
          P2_l[cc * 1280 + y * 40 + vv] = f2bf(acc[r]);
        }
      }
    }
  }
  __syncthreads();

  // stage 2
  for (int cw = w; cw < 8; cw += 4) {
    #pragma unroll
    for (int mi = 0; mi < 2; ++mi) {
      int y = mi * 16 + (l & 15);
      short8 a2 = *(const short8*)(P2_l + cw * 1280 + y * 40 + (l >> 4) * 8);
      #pragma unroll
      for (int nt2 = 0; nt2 < 2; ++nt2) {
        int u = nt2 * 16 + (l & 15);
        short8 b2 = *(const short8*)(As_l + u * 40 + (l >> 4) * 8);
        f32x4 acc = {0.f, 0.f, 0.f, 0.f};
        acc = __builtin_amdgcn_mfma_f32_16x16x32_bf16(a2, b2, acc, 0, 0, 0);
        #pragma unroll
        for (int r = 0; r < 4; ++r) {
          int yy = mi * 16 + (l >> 4) * 4 + r;
          int uu = nt2 * 16 + (l & 15);
          if (uu < 25)
            nu2[(size_t)(b * 128 + c0 + cw) * 800 + yy * 25 + uu] = f2bf(acc[r]);
        }
      }
    }
  }
}

// ---------------------------------------------------------------- kernel F (final GLU GEMM + bn)
// block: one batch b, 32 positions; 4 waves each own 64 o-rows of both Wcat1/Wcat2
__global__ __launch_bounds__(256) void k_final(
    const unsigned short* __restrict__ nu2, const float* __restrict__ h2,
    const unsigned short* __restrict__ Wc1, const unsigned short* __restrict__ Wc2,
    const float* __restrict__ b1p, const float* __restrict__ b2p,
    const float* __restrict__ bnsc, const float* __restrict__ bnsh,
    float* __restrict__ g2) {
  __shared__ __align__(16) unsigned short x_l[32 * 264];  // [p][k] pad 264 (2-way-free banking)
  int blk = blockIdx.x;
  int b = blk / 25;
  int p0 = (blk % 25) * 32;
  int tid = threadIdx.x;
  for (int i = tid; i < 8192; i += 256) {
    int p = i & 31, k = i >> 5;
    unsigned short val;
    if (k < 128) val = nu2[(size_t)(b * 128 + k) * 800 + p0 + p];
    else val = f2bf(h2[(size_t)(b * 128 + (k - 128)) * 800 + p0 + p]);
    x_l[p * 264 + k] = val;
  }
  __syncthreads();
  int w = tid >> 6, l = tid & 63;
  int ob = w * 64;
  f32x4 vzero = {0.f, 0.f, 0.f, 0.f};
  f32x4 acc1[4][2], acc2[4][2];
  #pragma unroll
  for (int mi = 0; mi < 4; ++mi)
    #pragma unroll
    for (int ni = 0; ni < 2; ++ni) { acc1[mi][ni] = vzero; acc2[mi][ni] = vzero; }
  #pragma unroll 1
  for (int ks = 0; ks < 8; ++ks) {
    int koff = ks * 32 + (l >> 4) * 8;
    short8 bfr[2];
    #pragma unroll
    for (int ni = 0; ni < 2; ++ni)
      bfr[ni] = *(const short8*)(x_l + (ni * 16 + (l & 15)) * 264 + koff);
    #pragma unroll
    for (int mi = 0; mi < 4; ++mi) {
      int row = ob + mi * 16 + (l & 15);
      short8 a1 = *(const short8*)(Wc1 + row * 256 + koff);
      short8 a2 = *(const short8*)(Wc2 + row * 256 + koff);
      #pragma unroll
      for (int ni = 0; ni < 2; ++ni) {
        acc1[mi][ni] = __builtin_amdgcn_mfma_f32_16x16x32_bf16(a1, bfr[ni], acc1[mi][ni], 0, 0, 0);
        acc2[mi][ni] = __builtin_amdgcn_mfma_f32_16x16x32_bf16(a2, bfr[ni], acc2[mi][ni], 0, 0, 0);
      }
    }
  }
  #pragma unroll
  for (int mi = 0; mi < 4; ++mi) {
    #pragma unroll
    for (int r = 0; r < 4; ++r) {
      int o = ob + mi * 16 + (l >> 4) * 4 + r;
      float bb1 = b1p[o], bb2 = b2p[o], sc = bnsc[o], sh = bnsh[o];
      #pragma unroll
      for (int ni = 0; ni < 2; ++ni) {
        int p = p0 + ni * 16 + (l & 15);
        float a = acc1[mi][ni][r] + bb1;
        float g = acc2[mi][ni][r] + bb2;
        float sig = 1.f / (1.f + __expf(-g));
        g2[(size_t)(b * 256 + o) * 800 + p] = (a * sig) * sc + sh;
      }
    }
  }
}

// ---------------------------------------------------------------- launch
extern "C" void kernel_launch(void* const* d_in, const int* in_sizes, int n_in,
                              void* d_out, int out_size, void* d_ws, size_t ws_size,
                              hipStream_t stream) {
  (void)in_sizes; (void)n_in; (void)out_size; (void)ws_size;
  const float* g1    = (const float*)d_in[0];
  const float* h2    = (const float*)d_in[1];
  const float* As_r  = (const float*)d_in[2];
  const float* At_r  = (const float*)d_in[3];
  const float* sc1_w = (const float*)d_in[4];
  const float* sc1_b = (const float*)d_in[5];
  const float* sc2_w = (const float*)d_in[6];
  const float* sc2_b = (const float*)d_in[7];
  const float* tc1_w = (const float*)d_in[8];
  const float* tc1_b = (const float*)d_in[9];
  const float* tc2_w = (const float*)d_in[10];
  const float* tc2_b = (const float*)d_in[11];
  const float* act_s = (const float*)d_in[12];
  const float* act_t = (const float*)d_in[13];
  const float* sp_w  = (const float*)d_in[14];
  const float* sp_b  = (const float*)d_in[15];
  const float* sp_gamma = (const float*)d_in[16];
  const float* sp_beta  = (const float*)d_in[17];
  const float* sp_mean  = (const float*)d_in[18];
  const float* sp_var   = (const float*)d_in[19];
  const float* W1_w = (const float*)d_in[20];
  const float* W1_b = (const float*)d_in[21];
  const float* W2_w = (const float*)d_in[22];
  const float* W2_b = (const float*)d_in[23];
  const float* bn_gamma = (const float*)d_in[24];
  const float* bn_beta  = (const float*)d_in[25];
  const float* bn_mean  = (const float*)d_in[26];
  const float* bn_var   = (const float*)d_in[27];

  float* out = (float*)d_out;
  float* out_g2     = out;
  float* out_As_at  = out + 26214400;
  float* out_At_at  = out + 26294400;
  float* out_As_act = out + 26818688;
  float* out_At_act = out + 26898688;

  char* ws = (char*)d_ws;
  float* sf    = (float*)(ws + 0);
  float* tf    = (float*)(ws + 1638400);
  float* As_ws = (float*)(ws + 5832704);
  float* Atev  = (float*)(ws + 6152704);
  unsigned short* Wc1 = (unsigned short*)(ws + 7201280);
  unsigned short* Wc2 = (unsigned short*)(ws + 7332352);
  float* b1pv  = (float*)(ws + 7463424);
  float* b2pv  = (float*)(ws + 7464448);
  float* bnscv = (float*)(ws + 7465472);
  float* bnshv = (float*)(ws + 7466496);
  unsigned short* g1vt = (unsigned short*)(ws + 7467520);
  unsigned short* nu2  = (unsigned short*)(ws + 59896320);

  k_means_tr<<<dim3(16384), dim3(256), 0, stream>>>(g1, sf, tf, g1vt);
  k_spat<<<dim3(128), dim3(256), 0, stream>>>(sf, sc1_w, sc1_b, sc2_w, sc2_b,
                                              As_r, act_s, As_ws, out_As_at, out_As_act);
  k_temp<<<dim3(128), dim3(256), 0, stream>>>(tf, tc1_w, tc1_b, tc2_w, tc2_b,
                                              At_r, act_t, Atev, out_At_at, out_At_act);
  k_prep<<<dim3(256), dim3(256), 0, stream>>>(W1_w, W1_b, W2_w, W2_b, sp_w, sp_b,
                                              sp_gamma, sp_beta, sp_mean, sp_var,
                                              bn_gamma, bn_beta, bn_mean, bn_var,
                                              Wc1, Wc2, b1pv, b2pv, bnscv, bnshv);
  k_nu2<<<dim3(2048), dim3(256), 0, stream>>>(g1vt, Atev, As_ws, nu2);
  k_final<<<dim3(3200), dim3(256), 0, stream>>>(nu2, h2, Wc1, Wc2, b1pv, b2pv,
                                                bnscv, bnshv, out_g2);
}